// Round 17
// baseline (491.920 us; speedup 1.0000x reference)
//
#include <hip/hip_runtime.h>
#include <cstdint>
#include <cstddef>

// ---------------- problem constants ----------------
#define VOCAB 32000
#define EMB   256
#define HID   1024
#define NB    16      // batch
#define SS    512     // seq
#define MTOK  (NB*SS) // 8192 tokens
#define KDIM  1024    // NM1*EMB = HID
#define NCHUNK 500    // 32000 / 64 cols per chunk
#define PSTRIDE 512   // padded chunk stride

typedef __bf16 bf16_t;
typedef bf16_t bf16x8 __attribute__((ext_vector_type(8)));
typedef float  f32x4  __attribute__((ext_vector_type(4)));
typedef float  f32x16 __attribute__((ext_vector_type(16)));
typedef int    i32x4  __attribute__((ext_vector_type(4)));
typedef int    i32x8  __attribute__((ext_vector_type(8)));

__device__ __forceinline__ unsigned short f32_to_bf16(float f) {
  union { float f; unsigned int u; } v; v.f = f;
  unsigned int u = v.u;
  unsigned int r = (u + 0x7FFFu + ((u >> 16) & 1u)) >> 16; // RNE
  return (unsigned short)r;
}

// f32 -> OCP e4m3fn, RNE, software (input assumed |x| <= 448)
__device__ __forceinline__ uint8_t f32_to_e4m3(float x) {
  union { float f; uint32_t u; } v; v.f = x;
  uint32_t s = (v.u >> 24) & 0x80u;
  int e = (int)((v.u >> 23) & 0xffu) - 127;
  uint32_t m = v.u & 0x7fffffu;
  if (e < -9) return (uint8_t)s;                  // -> 0
  if (e >= -6) {                                  // normal range
    uint32_t keep = m >> 20;
    uint32_t rest = m & 0xfffffu;
    keep += (rest > 0x80000u) || (rest == 0x80000u && (keep & 1u));
    if (keep == 8u) { keep = 0u; e += 1; }
    int code = ((e + 7) << 3) | (int)keep;
    if (code >= 0x7f) code = 0x7e;                // clamp to 448 (avoid NaN)
    return (uint8_t)(s | (uint32_t)code);
  }
  // subnormal
  uint32_t full = 0x800000u | m;
  int shift = 20 + (-6 - e);                      // 21..23
  uint32_t keep = full >> shift;
  uint32_t rest = full & ((1u << shift) - 1u);
  uint32_t half = 1u << (shift - 1);
  keep += (rest > half) || (rest == half && (keep & 1u));
  if (keep >= 8u) return (uint8_t)(s | 0x08u);
  return (uint8_t)(s | keep);
}

__device__ __forceinline__ void gload_lds16(const void* gsrc, void* ldst) {
  __builtin_amdgcn_global_load_lds(
      (__attribute__((address_space(1))) void*)gsrc,
      (__attribute__((address_space(3))) void*)ldst,
      16, 0, 0);
}

// Fragment-major record layout (per 32-row block rb, per K64-tile kt):
// 2048-B record at ((rb*16 + kt)*2048). Lane l's fragment bytes j (0..31):
//   src = Mat[row = 32*rb + (l&31)][kbyte = 64*kt + (l>>5)*32 + j]
//   j<16  -> record[l*16 + j]
//   j>=16 -> record[1024 + l*16 + (j-16)]
// A wave loads a frag with 2 coalesced global_load_dwordx4 (ofs 0 and 1024).

// ---------------- transpose + convert: in[R][C] f32 -> out[C][R] (bf16) ----------------
__global__ void k_transpose_bf16(const float* __restrict__ in,
                                 unsigned short* __restrict__ out,
                                 int R, int C) {
  __shared__ float tile[32][33];
  int bc = blockIdx.x * 32, br = blockIdx.y * 32;
  int tx = threadIdx.x & 31, ty = threadIdx.x >> 5;
#pragma unroll
  for (int i = 0; i < 32; i += 8)
    tile[ty + i][tx] = in[(size_t)(br + ty + i) * C + (bc + tx)];
  __syncthreads();
#pragma unroll
  for (int i = 0; i < 32; i += 8)
    out[(size_t)(bc + ty + i) * R + (br + tx)] = f32_to_bf16(tile[tx][ty + i]);
}

// ---------------- Wo -> fragment-major fp8 records ----------------
// grid (VOCAB/128, HID/64), 256 threads. Wo is [HID][VOCAB] f32.
__global__ void k_wo_frag(const float* __restrict__ Wo, uint8_t* __restrict__ Bf) {
  __shared__ uint8_t tile[64][128];  // [k-local][v-local]
  const int v0 = blockIdx.x * 128, k0 = blockIdx.y * 64;
  const int tid = threadIdx.x;
#pragma unroll
  for (int rr = 0; rr < 8; ++rr) {
    int row = rr * 8 + (tid >> 5);
    const float4 f = *(const float4*)&Wo[(size_t)(k0 + row) * VOCAB + v0 + (tid & 31) * 4];
    int vb = (tid & 31) * 4;
    tile[row][vb + 0] = f32_to_e4m3(f.x * 16.0f);
    tile[row][vb + 1] = f32_to_e4m3(f.y * 16.0f);
    tile[row][vb + 2] = f32_to_e4m3(f.z * 16.0f);
    tile[row][vb + 3] = f32_to_e4m3(f.w * 16.0f);
  }
  __syncthreads();
  const int rec = tid >> 6, l = tid & 63;
  const int vloc = rec * 32 + (l & 31);
  const int kb = (l >> 5) * 32;
  uint8_t* out = Bf + ((size_t)((blockIdx.x * 4 + rec) * 16 + blockIdx.y)) * 2048 + l * 16;
  union { uint8_t b[16]; i32x4 v; } lo, hi;
#pragma unroll
  for (int j = 0; j < 16; ++j) {
    lo.b[j] = tile[kb + j][vloc];
    hi.b[j] = tile[kb + 16 + j][vloc];
  }
  *(i32x4*)(out)        = lo.v;
  *(i32x4*)(out + 1024) = hi.v;
}

// ---------------- embedding gather ----------------
__global__ void k_gather_e(const int* __restrict__ text,
                           const float* __restrict__ embed,
                           unsigned short* __restrict__ E) {
  int t = blockIdx.x;
  int b = t >> 9, s = t & 511;
  int d = threadIdx.x; // 0..255
#pragma unroll
  for (int j = 0; j < 4; ++j) {
    int sidx = s + j - 4;
    int tok = (sidx >= 0) ? text[b * SS + sidx] : 0;
    float val = (tok != 0) ? embed[(size_t)tok * EMB + d] : 0.0f;
    E[(size_t)t * KDIM + j * EMB + d] = f32_to_bf16(val);
  }
}

// ---------------- FFN GEMM (128x128 tile; OUTQ=1 -> fp8 fragment-major records) -------
template<int OUTQ>
__global__ __launch_bounds__(256)
void k_gemm_ffn(const unsigned short* __restrict__ A,
                const unsigned short* __restrict__ Bt,
                const float* __restrict__ bias,
                void* __restrict__ Hout, int N) {
  __shared__ unsigned short As[128 * 32];
  __shared__ unsigned short Bs[128 * 32];
  const int tid  = threadIdx.x;
  const int bn   = blockIdx.x, bm = blockIdx.y;
  const int lane = tid & 63, wid = tid >> 6;
  const int wm = wid >> 1, wn = wid & 1;
  const int g = lane >> 4, c = lane & 15;

  f32x4 acc[4][4];
#pragma unroll
  for (int m = 0; m < 4; ++m)
#pragma unroll
    for (int n = 0; n < 4; ++n) { f32x4 z = {0.f, 0.f, 0.f, 0.f}; acc[m][n] = z; }

  const int arow = tid >> 2;
  const int slotb = ((tid & 3) ^ ((tid >> 3) & 3)) * 16;
  const char* gA0 = (const char*)A + ((size_t)(bm * 128 + arow) * KDIM) * 2 + slotb;
  const char* gA1 = gA0 + (size_t)64 * KDIM * 2;
  const char* gB0 = (const char*)Bt + ((size_t)(bn * 128 + arow) * KDIM) * 2 + slotb;
  const char* gB1 = gB0 + (size_t)64 * KDIM * 2;
  char* lA = (char*)As + tid * 16;
  char* lB = (char*)Bs + tid * 16;

  const int rs = (g ^ ((c >> 1) & 3)) * 8;

  for (int kt = 0; kt < KDIM / 32; ++kt) {
    const int kb = kt * 64;
    gload_lds16(gA0 + kb, lA);
    gload_lds16(gA1 + kb, lA + 4096);
    gload_lds16(gB0 + kb, lB);
    gload_lds16(gB1 + kb, lB + 4096);
    __syncthreads();

    bf16x8 af[4], bf[4];
#pragma unroll
    for (int m = 0; m < 4; ++m)
      af[m] = *(const bf16x8*)&As[(wm * 64 + m * 16 + c) * 32 + rs];
#pragma unroll
    for (int n = 0; n < 4; ++n)
      bf[n] = *(const bf16x8*)&Bs[(wn * 64 + n * 16 + c) * 32 + rs];
#pragma unroll
    for (int m = 0; m < 4; ++m)
#pragma unroll
      for (int n = 0; n < 4; ++n)
        acc[m][n] = __builtin_amdgcn_mfma_f32_16x16x32_bf16(af[m], bf[n], acc[m][n], 0, 0, 0);
    __syncthreads();
  }

#pragma unroll
  for (int n = 0; n < 4; ++n) {
    int colg = bn * 128 + wn * 64 + n * 16 + c;
    float bv = bias[colg];
#pragma unroll
    for (int m = 0; m < 4; ++m)
#pragma unroll
      for (int j = 0; j < 4; ++j) {
        int rowg = bm * 128 + wm * 64 + m * 16 + g * 4 + j;
        float v = acc[m][n][j] + bv;
        v = v > 0.f ? v : 0.f;
        if constexpr (OUTQ == 0) {
          ((unsigned short*)Hout)[(size_t)rowg * N + colg] = f32_to_bf16(v);
        } else {
          // fragment-major record store (see layout comment above)
          int ra = rowg >> 5, kt2 = colg >> 6;
          int l = (rowg & 31) + ((colg >> 5) & 1) * 32;
          int jj = colg & 31;
          size_t off = ((size_t)(ra * 16 + kt2)) * 2048 +
                       ((jj & 16) ? 1024 : 0) + l * 16 + (jj & 15);
          ((uint8_t*)Hout)[off] = f32_to_e4m3(v * 16.0f);
        }
      }
  }
}

// ---------------- vocab GEMM: MX-fp8, NO LDS, NO barriers, 64x128 per wave ----------
// R17 = R16 (per-wave 64x128, acc[2][4]=128 AGPR, loads/MFMA 2.0->1.5 KB, rolled
// loop) with the ds_swizzle patterns written as LITERALS (frontend requires
// constant integer -- R16's shifted pattern failed to compile).
__global__ __launch_bounds__(256, 2)
void k_gemm_vocab_mx(const uint8_t* __restrict__ Af,   // [256][16] records (A frags)
                     const uint8_t* __restrict__ Bf,   // [1000][16] records (B frags)
                     const float* __restrict__ bias,
                     float* __restrict__ psum,
                     float* __restrict__ tlog, const int* __restrict__ target) {
  const int tid  = threadIdx.x;
  const int lane = tid & 63, wid = tid >> 6;   // 4 waves
  const int wm = wid >> 1, wn = wid & 1;       // 2(M) x 2(N); per-wave out 64x128
  const int lr = lane & 31, kb = lane >> 5;

  // XCD-chunked swizzle; grid = 8000 = 64(bm) x 125(bn)
  const int t   = blockIdx.x;
  const int xcd = t & 7, i = t >> 3;           // i 0..999
  const int bm  = xcd * 8 + (i & 7);           // 0..63
  const int bn  = i >> 3;                      // 0..124

  f32x16 acc[2][4];
#pragma unroll
  for (int m = 0; m < 2; ++m)
#pragma unroll
    for (int n = 0; n < 4; ++n)
#pragma unroll
      for (int e = 0; e < 16; ++e) acc[m][n][e] = 0.f;

  // per-lane record pointers (advance 2048 B per K-tile)
  const uint8_t* pa0 = Af + ((size_t)(bm * 4 + wm * 2 + 0) * 16) * 2048 + lane * 16;
  const uint8_t* pa1 = Af + ((size_t)(bm * 4 + wm * 2 + 1) * 16) * 2048 + lane * 16;
  const uint8_t* pb0 = Bf + ((size_t)(bn * 8 + wn * 4 + 0) * 16) * 2048 + lane * 16;
  const uint8_t* pb1 = Bf + ((size_t)(bn * 8 + wn * 4 + 1) * 16) * 2048 + lane * 16;
  const uint8_t* pb2 = Bf + ((size_t)(bn * 8 + wn * 4 + 2) * 16) * 2048 + lane * 16;
  const uint8_t* pb3 = Bf + ((size_t)(bn * 8 + wn * 4 + 3) * 16) * 2048 + lane * 16;

#pragma unroll 1
  for (int kt = 0; kt < 16; ++kt) {
    i32x4 a0l = *(const i32x4*)(pa0);
    i32x4 a0h = *(const i32x4*)(pa0 + 1024);
    i32x4 a1l = *(const i32x4*)(pa1);
    i32x4 a1h = *(const i32x4*)(pa1 + 1024);
    i32x4 b0l = *(const i32x4*)(pb0);
    i32x4 b0h = *(const i32x4*)(pb0 + 1024);
    i32x4 b1l = *(const i32x4*)(pb1);
    i32x4 b1h = *(const i32x4*)(pb1 + 1024);
    i32x4 b2l = *(const i32x4*)(pb2);
    i32x4 b2h = *(const i32x4*)(pb2 + 1024);
    i32x4 b3l = *(const i32x4*)(pb3);
    i32x4 b3h = *(const i32x4*)(pb3 + 1024);
    pa0 += 2048; pa1 += 2048;
    pb0 += 2048; pb1 += 2048; pb2 += 2048; pb3 += 2048;

    i32x8 a0 = __builtin_shufflevector(a0l, a0h, 0, 1, 2, 3, 4, 5, 6, 7);
    i32x8 a1 = __builtin_shufflevector(a1l, a1h, 0, 1, 2, 3, 4, 5, 6, 7);
    i32x8 b0 = __builtin_shufflevector(b0l, b0h, 0, 1, 2, 3, 4, 5, 6, 7);
    i32x8 b1 = __builtin_shufflevector(b1l, b1h, 0, 1, 2, 3, 4, 5, 6, 7);
    i32x8 b2 = __builtin_shufflevector(b2l, b2h, 0, 1, 2, 3, 4, 5, 6, 7);
    i32x8 b3 = __builtin_shufflevector(b3l, b3h, 0, 1, 2, 3, 4, 5, 6, 7);

    __builtin_amdgcn_s_setprio(1);
    acc[0][0] = __builtin_amdgcn_mfma_scale_f32_32x32x64_f8f6f4(
        a0, b0, acc[0][0], 0, 0, 0, 123, 0, 123);
    acc[0][1] = __builtin_amdgcn_mfma_scale_f32_32x32x64_f8f6f4(
        a0, b1, acc[0][1], 0, 0, 0, 123, 0, 123);
    acc[0][2] = __builtin_amdgcn_mfma_scale_f32_32x32x64_f8f6f4(
        a0, b2, acc[0][2], 0, 0, 0, 123, 0, 123);
    acc[0][3] = __builtin_amdgcn_mfma_scale_f32_32x32x64_f8f6f4(
        a0, b3, acc[0][3], 0, 0, 0, 123, 0, 123);
    acc[1][0] = __builtin_amdgcn_mfma_scale_f32_32x32x64_f8f6f4(
        a1, b0, acc[1][0], 0, 0, 0, 123, 0, 123);
    acc[1][1] = __builtin_amdgcn_mfma_scale_f32_32x32x64_f8f6f4(
        a1, b1, acc[1][1], 0, 0, 0, 123, 0, 123);
    acc[1][2] = __builtin_amdgcn_mfma_scale_f32_32x32x64_f8f6f4(
        a1, b2, acc[1][2], 0, 0, 0, 123, 0, 123);
    acc[1][3] = __builtin_amdgcn_mfma_scale_f32_32x32x64_f8f6f4(
        a1, b3, acc[1][3], 0, 0, 0, 123, 0, 123);
    __builtin_amdgcn_s_setprio(0);
  }

  // ---- epilogue: per-64-col-chunk sum of exp (no max; logits bounded) ----
  // C/D 32x32 layout: col = lane&31, row = (reg&3) + 8*(reg>>2) + 4*(lane>>5)
  const int colbase = bn * 256 + wn * 128;
  const int chunk0 = bn * 4 + wn * 2;
  float bov[4];
#pragma unroll
  for (int n = 0; n < 4; ++n) bov[n] = bias[colbase + n * 32 + lr];
#pragma unroll
  for (int m = 0; m < 2; ++m) {
#pragma unroll
    for (int reg = 0; reg < 16; ++reg) {
      int rowg = bm * 128 + wm * 64 + m * 32 + (reg & 3) + 8 * (reg >> 2) + 4 * kb;
      float v0 = acc[m][0][reg] + bov[0];
      float v1 = acc[m][1][reg] + bov[1];
      float v2 = acc[m][2][reg] + bov[2];
      float v3 = acc[m][3][reg] + bov[3];
      float e01 = __expf(v0) + __expf(v1);
      float e23 = __expf(v2) + __expf(v3);
      union { float f; int i; } a_, b_;
      // 5-step butterfly within each 32-lane group; LITERAL BitMode patterns:
      // offset = (xor<<10) | 0x1F  (and=0x1F, or=0) -> lane ^= xor within group
      a_.f = e01; b_.i = __builtin_amdgcn_ds_swizzle(a_.i, 0x041F); e01 += b_.f;
      a_.f = e23; b_.i = __builtin_amdgcn_ds_swizzle(a_.i, 0x041F); e23 += b_.f;
      a_.f = e01; b_.i = __builtin_amdgcn_ds_swizzle(a_.i, 0x081F); e01 += b_.f;
      a_.f = e23; b_.i = __builtin_amdgcn_ds_swizzle(a_.i, 0x081F); e23 += b_.f;
      a_.f = e01; b_.i = __builtin_amdgcn_ds_swizzle(a_.i, 0x101F); e01 += b_.f;
      a_.f = e23; b_.i = __builtin_amdgcn_ds_swizzle(a_.i, 0x101F); e23 += b_.f;
      a_.f = e01; b_.i = __builtin_amdgcn_ds_swizzle(a_.i, 0x201F); e01 += b_.f;
      a_.f = e23; b_.i = __builtin_amdgcn_ds_swizzle(a_.i, 0x201F); e23 += b_.f;
      a_.f = e01; b_.i = __builtin_amdgcn_ds_swizzle(a_.i, 0x401F); e01 += b_.f;
      a_.f = e23; b_.i = __builtin_amdgcn_ds_swizzle(a_.i, 0x401F); e23 += b_.f;
      if (lr == 0) {
        psum[(size_t)rowg * PSTRIDE + chunk0 + 0] = e01;
        psum[(size_t)rowg * PSTRIDE + chunk0 + 1] = e23;
      }
      int cw = target[rowg] - colbase;
      if (cw >= 0 && cw < 128 && lr == (cw & 31)) {
        int nn = cw >> 5;
        tlog[rowg] = (nn == 0) ? v0 : (nn == 1) ? v1 : (nn == 2) ? v2 : v3;
      }
    }
  }
}

// ---------------- combine per-chunk sums -> nll per row ----------------
__global__ void k_reduce_nll(const float* __restrict__ psum,
                             const float* __restrict__ tlog,
                             float* __restrict__ nll) {
  int row = blockIdx.x;
  int lane = threadIdx.x; // 64
  float L = 0.f;
  for (int ch = lane; ch < NCHUNK; ch += 64)
    L += psum[(size_t)row * PSTRIDE + ch];
#pragma unroll
  for (int s = 1; s < 64; s <<= 1) L += __shfl_xor(L, s);
  if (lane == 0) nll[row] = logf(L) - tlog[row];
}

// ---------------- masked per-step mean -> scalar loss ----------------
__global__ void k_loss(const int* __restrict__ target,
                       const float* __restrict__ nll,
                       float* __restrict__ out) {
  __shared__ float red[SS];
  int s = threadIdx.x; // 512
  float sl = 0.f, cnt = 0.f;
#pragma unroll
  for (int b = 0; b < NB; ++b) {
    int idx = b * SS + s;
    if (target[idx] != 0) { sl += nll[idx]; cnt += 1.f; }
  }
  red[s] = sl / fmaxf(cnt, 1.f);
  __syncthreads();
  for (int st = 256; st > 0; st >>= 1) {
    if (s < st) red[s] += red[s + st];
    __syncthreads();
  }
  if (s == 0) out[0] = red[0] / (float)SS;
}

// ---------------- launch ----------------
extern "C" void kernel_launch(void* const* d_in, const int* in_sizes, int n_in,
                              void* d_out, int out_size, void* d_ws, size_t ws_size,
                              hipStream_t stream) {
  (void)in_sizes; (void)n_in; (void)out_size; (void)ws_size;
  const int*   text   = (const int*)d_in[0];
  const int*   target = (const int*)d_in[1];
  const float* embed  = (const float*)d_in[2];
  const float* W1     = (const float*)d_in[3];
  const float* b1     = (const float*)d_in[4];
  const float* W2     = (const float*)d_in[5];
  const float* b2     = (const float*)d_in[6];
  const float* Wo     = (const float*)d_in[7];
  const float* bo     = (const float*)d_in[8];
  float* out = (float*)d_out;
  char* ws = (char*)d_ws;

  const size_t SZ_E = (size_t)MTOK * KDIM * 2;          // 16.78 MB (bf16)
  unsigned short* E   = (unsigned short*)(ws);
  unsigned short* H1  = (unsigned short*)(ws + SZ_E);
  uint8_t*        H2Q = (uint8_t*)(ws + 2 * SZ_E);      // fp8 A-records, 8.39 MB
  char* p = ws + 2 * SZ_E + (size_t)MTOK * KDIM;
  unsigned short* W1t = (unsigned short*)p;  p += (size_t)HID * HID * 2;
  unsigned short* W2t = (unsigned short*)p;  p += (size_t)HID * HID * 2;
  uint8_t*        WoQ = (uint8_t*)p;         p += (size_t)VOCAB * HID;   // fp8 B-records, 32.77 MB
  float* tlog = (float*)p;                   p += (size_t)MTOK * 4;
  float* nll  = (float*)p;
  float* psum = (float*)H1;  // H1 dead after GEMM2

  k_transpose_bf16<<<dim3(HID / 32, HID / 32), 256, 0, stream>>>(W1, W1t, HID, HID);
  k_transpose_bf16<<<dim3(HID / 32, HID / 32), 256, 0, stream>>>(W2, W2t, HID, HID);
  k_wo_frag<<<dim3(VOCAB / 128, HID / 64), 256, 0, stream>>>(Wo, WoQ);
  k_gather_e<<<MTOK, 256, 0, stream>>>(text, embed, E);

  k_gemm_ffn<0><<<dim3(HID / 128, MTOK / 128), 256, 0, stream>>>(E, W1t, b1, (void*)H1, HID);
  k_gemm_ffn<1><<<dim3(HID / 128, MTOK / 128), 256, 0, stream>>>(H1, W2t, b2, (void*)H2Q, HID);

  k_gemm_vocab_mx<<<dim3((MTOK / 128) * (VOCAB / 256)), 256, 0, stream>>>(
      H2Q, WoQ, bo, psum, tlog, target);

  k_reduce_nll<<<MTOK, 64, 0, stream>>>(psum, tlog, nll);
  k_loss<<<1, SS, 0, stream>>>(target, nll, out);
}